// Round 15
// baseline (4630.325 us; speedup 1.0000x reference)
//
#include <hip/hip_runtime.h>
#include <hip/hip_bf16.h>
#include <cstdint>
#include <cstddef>

// Problem sizes (fixed)
#define BB 64
#define SS 1024
#define II 1024
#define HH 1024
#define G3 3072   // 3*HH

typedef float  f32x4  __attribute__((ext_vector_type(4)));
typedef short  bf16x8 __attribute__((ext_vector_type(8)));

__device__ __forceinline__ unsigned short f2b(float f) {
    unsigned u = __float_as_uint(f);
    u += 0x7FFFu + ((u >> 16) & 1u);   // RNE
    return (unsigned short)(u >> 16);
}
__device__ __forceinline__ float b2f(unsigned short s) {
    return __uint_as_float(((unsigned)s) << 16);
}

// ---------------------------------------------------------------------------
// Kernel 0: bf16 prepass — xb = bf16(x), wb = bf16(W_ih). One pass, HBM-bound.
// ---------------------------------------------------------------------------
__global__ __launch_bounds__(256)
void conv_b16(const float* __restrict__ x, const float* __restrict__ w,
              unsigned short* __restrict__ xb, unsigned short* __restrict__ wb)
{
    const size_t XN = (size_t)BB * SS * II;     // 67108864
    const size_t WN = (size_t)G3 * II;          // 3145728
    size_t i = ((size_t)blockIdx.x * 256 + threadIdx.x) * 4;
    if (i < XN) {
        float4 v = *reinterpret_cast<const float4*>(x + i);
        uint2 p;
        p.x = (unsigned)f2b(v.x) | ((unsigned)f2b(v.y) << 16);
        p.y = (unsigned)f2b(v.z) | ((unsigned)f2b(v.w) << 16);
        *reinterpret_cast<uint2*>(xb + i) = p;
    } else {
        size_t j = i - XN;
        if (j < WN) {
            float4 v = *reinterpret_cast<const float4*>(w + j);
            uint2 p;
            p.x = (unsigned)f2b(v.x) | ((unsigned)f2b(v.y) << 16);
            p.y = (unsigned)f2b(v.z) | ((unsigned)f2b(v.w) << 16);
            *reinterpret_cast<uint2*>(wb + j) = p;
        }
    }
}

// ---------------------------------------------------------------------------
// Kernel 2: init  (reset counters, h16[buf0] = bf16(h0))
// ---------------------------------------------------------------------------
__global__ __launch_bounds__(256)
void gru_init(const float* __restrict__ h0, unsigned short* __restrict__ h16,
              int* __restrict__ flags)
{
    int i = blockIdx.x * 256 + threadIdx.x;   // i = b*1024 + j, 65536 total
    int b = i >> 10, j = i & 1023;
    int dst = (b >> 4) * 16384 + (j >> 3) * 128 + (b & 15) * 8 + (j & 7);
    h16[dst] = f2b(h0[i]);
    if (i < 2304) flags[i] = 0;   // 128 wave-counters @ 64B stride + chunk ctrs
}

// ---------------------------------------------------------------------------
// One 128x128 GEMM tile job: gi16[m0..m0+128, n0..n0+128) = xb @ wb^T + bias,
// written as packed bf16 pairs via sc1 (agent) stores.
// ---------------------------------------------------------------------------
__device__ __forceinline__ void gemm_tile(
    const unsigned short* __restrict__ XB, const unsigned short* __restrict__ WB,
    const float* __restrict__ bias, unsigned short* __restrict__ gi16,
    short* As, short* Bs, int m0, int n0, int t, int lane, int wave)
{
    const int lr = lane >> 3;             // 0..7
    const int lc = (lane & 7) * 8;        // bf16 col
    const int mb = (wave & 1) * 64;
    const int nb = (wave >> 1) * 32;

    f32x4 acc[4][2] = {};
    for (int k0 = 0; k0 < II; k0 += 64) {
        __syncthreads();
        #pragma unroll
        for (int p = 0; p < 2; ++p) {
            int sg = p * 8 + wave;        // 0..15, wave-uniform
            const unsigned short* ga = XB + (size_t)(m0 + sg * 8 + lr) * II + k0 + lc;
            const unsigned short* gb = WB + (size_t)(n0 + sg * 8 + lr) * II + k0 + lc;
            __builtin_amdgcn_global_load_lds(
                (const __attribute__((address_space(1))) void*)ga,
                (__attribute__((address_space(3))) void*)(As + sg * 512), 16, 0, 0);
            __builtin_amdgcn_global_load_lds(
                (const __attribute__((address_space(1))) void*)gb,
                (__attribute__((address_space(3))) void*)(Bs + sg * 512), 16, 0, 0);
        }
        __syncthreads();
        #pragma unroll
        for (int ks = 0; ks < 2; ++ks) {
            bf16x8 af[4], bf[2];
            #pragma unroll
            for (int i = 0; i < 4; ++i)
                af[i] = *reinterpret_cast<const bf16x8*>(
                    As + (mb + i * 16 + (lane & 15)) * 64 + ks * 32 + (lane >> 4) * 8);
            #pragma unroll
            for (int i = 0; i < 2; ++i)
                bf[i] = *reinterpret_cast<const bf16x8*>(
                    Bs + (nb + i * 16 + (lane & 15)) * 64 + ks * 32 + (lane >> 4) * 8);
            #pragma unroll
            for (int mi = 0; mi < 4; ++mi)
                #pragma unroll
                for (int ni = 0; ni < 2; ++ni)
                    acc[mi][ni] = __builtin_amdgcn_mfma_f32_16x16x32_bf16(
                        af[mi], bf[ni], acc[mi][ni], 0, 0, 0);
        }
    }
    #pragma unroll
    for (int ni = 0; ni < 2; ++ni) {
        int ncol = n0 + nb + ni * 16 + (lane & 15);
        float bv = bias[ncol];
        #pragma unroll
        for (int mi = 0; mi < 4; ++mi) {
            int mrow = m0 + mb + mi * 16 + ((lane >> 4) << 2);
            #pragma unroll
            for (int e = 0; e < 4; ++e) {
                float v = acc[mi][ni][e] + bv;
                unsigned short hb = f2b(v);
                unsigned pv = (unsigned)__shfl_xor((int)(unsigned)hb, 1);
                if (!(lane & 1)) {
                    unsigned word = (unsigned)hb | (pv << 16);
                    __hip_atomic_store(
                        (unsigned*)(gi16 + (size_t)(mrow + e) * G3 + ncol),
                        word, __ATOMIC_RELAXED, __HIP_MEMORY_SCOPE_AGENT);
                }
            }
        }
    }
}

// ---------------------------------------------------------------------------
// Kernel F: FUSED producer-consumer. Cooperative 256 blocks x 512 threads.
// LDS 104448 B -> exactly 1 block/CU (deterministic placement).
// Phase 0 (ALL blocks): 6 chunk-0 tiles each -> done[0] += 1 (target 256).
// Then bid<128: scan role; bid>=128: worker role (chunks 1..7).
// Scan sync (this round): ONE barrier per step. part[] is parity
// double-buffered (LDS WAR covered by bar1 of the following step), and the
// per-block t0-flag is replaced by a monotone per-block counter that each
// wave bumps after its OWN vmcnt(0) drain — block jb finished step s-1 iff
// cnt[jb] >= 8*s. Consumers fine-poll their 4 producer blocks' counters.
// WAR on h parity slabs: publish is after bar1, and the union of the 8
// waves' polls covers all 32 blocks of the group (counters monotone).
// ---------------------------------------------------------------------------
__global__ __launch_bounds__(512, 1)
void gru_fused(unsigned short* __restrict__ gi16,
               const unsigned short* __restrict__ XB,
               const unsigned short* __restrict__ WB, const float* __restrict__ bias,
               const float* __restrict__ Whh, const float* __restrict__ h0,
               unsigned short* __restrict__ h16, int* __restrict__ flags,
               float* __restrict__ out)
{
    __shared__ char smem[104448];
    const int t    = threadIdx.x;
    const int lane = t & 63;
    const int wave = t >> 6;          // 0..7
    const int bid  = blockIdx.x;

    short* As = (short*)smem;
    short* Bs = (short*)(smem + 16384);

    // ---- phase 0: all 256 blocks produce chunk 0 ----
    #pragma unroll 1
    for (int q = 0; q < 6; ++q) {
        int tile = bid * 6 + q;          // 0..1535
        int b = tile / 24, n = tile % 24;
        gemm_tile(XB, WB, bias, gi16, As, Bs, b * 1024, n * 128, t, lane, wave);
    }
    asm volatile("s_waitcnt vmcnt(0)" ::: "memory");
    __syncthreads();                     // all sc1 stores drained, smem free
    if (t == 0)
        __hip_atomic_fetch_add(&flags[2048], 1,
                               __ATOMIC_RELAXED, __HIP_MEMORY_SCOPE_AGENT);

    if (bid >= 128) {
        // =================== worker role: chunks 1..7 ===================
        const int wkr = bid - 128;
        #pragma unroll 1
        for (int jj = 0; jj < 84; ++jj) {
            int c   = 1 + jj / 12;
            int idx = (jj % 12) * 128 + wkr;     // 0..1535 within chunk
            int b = idx / 24, n = idx % 24;
            gemm_tile(XB, WB, bias, gi16, As, Bs,
                      b * 1024 + c * 128, n * 128, t, lane, wave);
            if ((jj % 12) == 11) {
                asm volatile("s_waitcnt vmcnt(0)" ::: "memory");
                __syncthreads();
                if (t == 0)
                    __hip_atomic_fetch_add(&flags[2048 + (c << 4)], 1,
                                           __ATOMIC_RELAXED, __HIP_MEMORY_SCOPE_AGENT);
            }
        }
        return;
    }

    // =================== scan role ===================
    auto part = reinterpret_cast<float(*)[8][6][4][68]>(smem);  // [2][8][6][4][68]

    const int group = bid & 3;
    const int jb    = bid >> 2;        // 0..31

    bf16x8 wf[4][6];
    #pragma unroll
    for (int kc = 0; kc < 4; ++kc) {
        #pragma unroll
        for (int nt = 0; nt < 6; ++nt) {
            int rowg = (nt >> 1) * HH + jb * 32 + (nt & 1) * 16 + (lane & 15);
            int k    = wave * 128 + kc * 32 + ((lane >> 4) << 3);
            const float4* src = reinterpret_cast<const float4*>(Whh + (size_t)rowg * HH + k);
            float4 f0 = src[0], f1 = src[1];
            bf16x8 w;
            w[0] = (short)f2b(f0.x); w[1] = (short)f2b(f0.y);
            w[2] = (short)f2b(f0.z); w[3] = (short)f2b(f0.w);
            w[4] = (short)f2b(f1.x); w[5] = (short)f2b(f1.y);
            w[6] = (short)f2b(f1.z); w[7] = (short)f2b(f1.w);
            wf[kc][nt] = w;
        }
    }

    const int b_l = t >> 5;
    const int j_l = t & 31;
    const int b_g = (group << 4) + b_l;
    const int j_g = (jb << 5) + j_l;
    float hreg = h0[b_g * HH + j_g];

    const int frag_base = (wave * 16 + (lane >> 4)) * 256 + ((lane & 15) << 4);
    const int prod_off  = ((j_g >> 3) << 8) + (b_l << 4) + ((j_g & 7) << 1);

    const int nt_r = j_l >> 4;
    const int lp   = ((b_l >> 2) << 4) | (j_l & 15);
    const int e_r  = b_l & 3;

    const int poll_fi = ((group << 5) | (wave << 2) | (lane & 3)) << 4;
    int* const my_cnt = &flags[((group << 5) | jb) << 4];
    const int jeven = j_g & ~1;
    const int jsel  = (j_g & 1) << 4;   // 0 or 16 bit shift

    for (int s = 0; s < SS; ++s) {
        // chunk gate: gi chunk (s>>7) fully produced (chunk0 target 256)
        if ((s & 127) == 0) {
            const int target = (s == 0) ? 256 : 128;
            if (t == 0) {
                while (__hip_atomic_load(&flags[2048 + ((s >> 7) << 4)],
                                         __ATOMIC_RELAXED, __HIP_MEMORY_SCOPE_AGENT) < target)
                    __builtin_amdgcn_s_sleep(2);
            }
            __syncthreads();
        }

        const int p = s & 1;
        const char* rslab = (const char*)(h16 + (size_t)p * 65536 + group * 16384);
        unsigned short* wslab = h16 + (size_t)(p ^ 1) * 65536 + group * 16384;

        // prefetch gi (bf16 pairs, sc1: fresh across XCDs)
        size_t gib = ((size_t)b_g * SS + s) * G3;
        unsigned wr = __hip_atomic_load((const unsigned*)(gi16 + gib + jeven),
                                        __ATOMIC_RELAXED, __HIP_MEMORY_SCOPE_AGENT);
        unsigned wz = __hip_atomic_load((const unsigned*)(gi16 + gib + HH + jeven),
                                        __ATOMIC_RELAXED, __HIP_MEMORY_SCOPE_AGENT);
        unsigned wn = __hip_atomic_load((const unsigned*)(gi16 + gib + 2 * HH + jeven),
                                        __ATOMIC_RELAXED, __HIP_MEMORY_SCOPE_AGENT);
        float ir  = b2f((unsigned short)(wr >> jsel));
        float iz  = b2f((unsigned short)(wz >> jsel));
        float inn = b2f((unsigned short)(wn >> jsel));

        // fine poll: this wave's 4 producer blocks, counter target 8*s
        if (s > 0) {
            const int tgt = s << 3;
            while (true) {
                int v = __hip_atomic_load(&flags[poll_fi], __ATOMIC_RELAXED,
                                          __HIP_MEMORY_SCOPE_AGENT);
                if (__all(v >= tgt)) break;
            }
            asm volatile("" ::: "memory");
        }

        unsigned long long hv[8];
        #pragma unroll
        for (int kc = 0; kc < 4; ++kc) {
            const unsigned long long* q =
                (const unsigned long long*)(rslab + frag_base + kc * 1024);
            hv[2 * kc]     = __hip_atomic_load(q,     __ATOMIC_RELAXED,
                                               __HIP_MEMORY_SCOPE_AGENT);
            hv[2 * kc + 1] = __hip_atomic_load(q + 1, __ATOMIC_RELAXED,
                                               __HIP_MEMORY_SCOPE_AGENT);
        }

        f32x4 acc[6] = {};
        #pragma unroll
        for (int kc = 0; kc < 4; ++kc) {
            union { unsigned long long q[2]; bf16x8 v; } u;
            u.q[0] = hv[2 * kc]; u.q[1] = hv[2 * kc + 1];
            #pragma unroll
            for (int nt = 0; nt < 6; ++nt)
                acc[nt] = __builtin_amdgcn_mfma_f32_16x16x32_bf16(u.v, wf[kc][nt], acc[nt], 0, 0, 0);
        }

        #pragma unroll
        for (int nt = 0; nt < 6; ++nt)
            #pragma unroll
            for (int e = 0; e < 4; ++e)
                part[p][wave][nt][e][lane] = acc[nt][e];
        __syncthreads();   // bar1 — the ONLY barrier per step

        float hr = 0.f, hz = 0.f, hn = 0.f;
        #pragma unroll
        for (int w = 0; w < 8; ++w) {
            hr += part[p][w][0 + nt_r][e_r][lp];
            hz += part[p][w][2 + nt_r][e_r][lp];
            hn += part[p][w][4 + nt_r][e_r][lp];
        }

        float r  = __builtin_amdgcn_rcpf(1.f + __expf(-(ir + hr)));
        float z  = __builtin_amdgcn_rcpf(1.f + __expf(-(iz + hz)));
        float e2 = __expf(2.f * (inn + r * hn));
        float n  = 1.f - 2.f * __builtin_amdgcn_rcpf(e2 + 1.f);
        float hnew = (1.f - z) * n + z * hreg;
        hreg = hnew;

        // publish h (after bar1 -> parity WAR safe)
        unsigned short myb = f2b(hnew);
        unsigned pv = (unsigned)__shfl_xor((int)(unsigned)myb, 1);
        if (!(j_l & 1)) {
            unsigned val = ((unsigned)myb) | (pv << 16);
            __hip_atomic_store((unsigned*)((char*)wslab + prod_off), val,
                               __ATOMIC_RELAXED, __HIP_MEMORY_SCOPE_AGENT);
        }

        // per-wave release: drain own publishes, bump block counter
        asm volatile("s_waitcnt vmcnt(0)" ::: "memory");
        if (lane == 0)
            __hip_atomic_fetch_add(my_cnt, 1,
                                   __ATOMIC_RELAXED, __HIP_MEMORY_SCOPE_AGENT);

        // out store AFTER the release — not part of the recurrence
        out[((size_t)b_g * SS + s) * HH + j_g] = hnew;
    }

    out[(size_t)BB * SS * HH + (size_t)b_g * HH + j_g] = hreg;
}

// ---------------------------------------------------------------------------
// Fallback (ws too small for xb/wb): old serial inline-convert GEMM + scan.
// ---------------------------------------------------------------------------
template<int GI_BF16>
__global__ __launch_bounds__(256)
void gi_gemm(const float* __restrict__ X, const float* __restrict__ W,
             const float* __restrict__ bias, void* __restrict__ gi_out)
{
    __shared__ short As[128][40];
    __shared__ short Bs[128][40];

    const int t    = threadIdx.x;
    const int lane = t & 63;
    const int wave = t >> 6;
    const int m0   = blockIdx.y * 128;
    const int n0   = blockIdx.x * 128;

    f32x4 acc[4][4] = {};

    for (int k0 = 0; k0 < II; k0 += 32) {
        __syncthreads();
        #pragma unroll
        for (int q = 0; q < 2; ++q) {
            int row = (t >> 2) + 64 * q;
            int col = (t & 3) * 8;
            const float4* ap = reinterpret_cast<const float4*>(X + (size_t)(m0 + row) * II + k0 + col);
            const float4* bp = reinterpret_cast<const float4*>(W + (size_t)(n0 + row) * II + k0 + col);
            float4 a0 = ap[0], a1 = ap[1];
            float4 b0 = bp[0], b1 = bp[1];
            bf16x8 av, bv;
            av[0] = (short)f2b(a0.x); av[1] = (short)f2b(a0.y);
            av[2] = (short)f2b(a0.z); av[3] = (short)f2b(a0.w);
            av[4] = (short)f2b(a1.x); av[5] = (short)f2b(a1.y);
            av[6] = (short)f2b(a1.z); av[7] = (short)f2b(a1.w);
            bv[0] = (short)f2b(b0.x); bv[1] = (short)f2b(b0.y);
            bv[2] = (short)f2b(b0.z); bv[3] = (short)f2b(b0.w);
            bv[4] = (short)f2b(b1.x); bv[5] = (short)f2b(b1.y);
            bv[6] = (short)f2b(b1.z); bv[7] = (short)f2b(b1.w);
            *reinterpret_cast<bf16x8*>(&As[row][col]) = av;
            *reinterpret_cast<bf16x8*>(&Bs[row][col]) = bv;
        }
        __syncthreads();

        const int mb = (wave & 1) * 64;
        const int nb = (wave >> 1) * 64;
        bf16x8 af[4], bf[4];
        #pragma unroll
        for (int i = 0; i < 4; ++i) {
            af[i] = *reinterpret_cast<const bf16x8*>(&As[mb + i * 16 + (lane & 15)][(lane >> 4) * 8]);
            bf[i] = *reinterpret_cast<const bf16x8*>(&Bs[nb + i * 16 + (lane & 15)][(lane >> 4) * 8]);
        }
        #pragma unroll
        for (int mi = 0; mi < 4; ++mi)
            #pragma unroll
            for (int ni = 0; ni < 4; ++ni)
                acc[mi][ni] = __builtin_amdgcn_mfma_f32_16x16x32_bf16(af[mi], bf[ni], acc[mi][ni], 0, 0, 0);
    }

    const int mb = (wave & 1) * 64;
    const int nb = (wave >> 1) * 64;
    #pragma unroll
    for (int ni = 0; ni < 4; ++ni) {
        int ncol = n0 + nb + ni * 16 + (lane & 15);
        float bv = bias[ncol];
        #pragma unroll
        for (int mi = 0; mi < 4; ++mi) {
            int mrow = m0 + mb + mi * 16 + ((lane >> 4) << 2);
            #pragma unroll
            for (int e = 0; e < 4; ++e) {
                float v = acc[mi][ni][e] + bv;
                size_t idx = (size_t)(mrow + e) * G3 + ncol;
                if (GI_BF16) ((unsigned short*)gi_out)[idx] = f2b(v);
                else         ((float*)gi_out)[idx] = v;
            }
        }
    }
}

template<int GI_BF16>
__global__ __launch_bounds__(512, 1)
void gru_scan(const void* __restrict__ gi_v, const float* __restrict__ Whh,
              const float* __restrict__ h0, unsigned short* __restrict__ h16,
              int* __restrict__ flags, float* __restrict__ out)
{
    const int t     = threadIdx.x;
    const int lane  = t & 63;
    const int wave  = t >> 6;
    const int bid   = blockIdx.x;
    const int group = bid & 3;
    const int jb    = bid >> 2;

    __shared__ float part[8][6][4][68];

    bf16x8 wf[4][6];
    #pragma unroll
    for (int kc = 0; kc < 4; ++kc) {
        #pragma unroll
        for (int nt = 0; nt < 6; ++nt) {
            int rowg = (nt >> 1) * HH + jb * 32 + (nt & 1) * 16 + (lane & 15);
            int k    = wave * 128 + kc * 32 + ((lane >> 4) << 3);
            const float4* src = reinterpret_cast<const float4*>(Whh + (size_t)rowg * HH + k);
            float4 f0 = src[0], f1 = src[1];
            bf16x8 w;
            w[0] = (short)f2b(f0.x); w[1] = (short)f2b(f0.y);
            w[2] = (short)f2b(f0.z); w[3] = (short)f2b(f0.w);
            w[4] = (short)f2b(f1.x); w[5] = (short)f2b(f1.y);
            w[6] = (short)f2b(f1.z); w[7] = (short)f2b(f1.w);
            wf[kc][nt] = w;
        }
    }

    const int b_l = t >> 5;
    const int j_l = t & 31;
    const int b_g = (group << 4) + b_l;
    const int j_g = (jb << 5) + j_l;
    float hreg = h0[b_g * HH + j_g];

    const int frag_base = (wave * 16 + (lane >> 4)) * 256 + ((lane & 15) << 4);
    const int prod_off  = ((j_g >> 3) << 8) + (b_l << 4) + ((j_g & 7) << 1);

    const int nt_r = j_l >> 4;
    const int lp   = ((b_l >> 2) << 4) | (j_l & 15);
    const int e_r  = b_l & 3;

    const int poll_fi = ((group << 5) | (wave << 2) | (lane & 3)) << 4;

    for (int s = 0; s < SS; ++s) {
        const int p = s & 1;
        const char* rslab = (const char*)(h16 + (size_t)p * 65536 + group * 16384);
        unsigned short* wslab = h16 + (size_t)(p ^ 1) * 65536 + group * 16384;

        size_t gib = ((size_t)b_g * SS + s) * G3;
        float ir, iz, inn;
        if (GI_BF16) {
            const unsigned short* g16 = (const unsigned short*)gi_v;
            ir  = b2f(g16[gib + j_g]);
            iz  = b2f(g16[gib + HH + j_g]);
            inn = b2f(g16[gib + 2 * HH + j_g]);
        } else {
            const float* g32 = (const float*)gi_v;
            ir  = g32[gib + j_g];
            iz  = g32[gib + HH + j_g];
            inn = g32[gib + 2 * HH + j_g];
        }

        if (s > 0) {
            while (true) {
                int v = __hip_atomic_load(&flags[poll_fi], __ATOMIC_RELAXED,
                                          __HIP_MEMORY_SCOPE_AGENT);
                if (__all(v >= s)) break;
            }
            asm volatile("" ::: "memory");
        }

        unsigned long long hv[8];
        #pragma unroll
        for (int kc = 0; kc < 4; ++kc) {
            const unsigned long long* q =
                (const unsigned long long*)(rslab + frag_base + kc * 1024);
            hv[2 * kc]     = __hip_atomic_load(q,     __ATOMIC_RELAXED,
                                               __HIP_MEMORY_SCOPE_AGENT);
            hv[2 * kc + 1] = __hip_atomic_load(q + 1, __ATOMIC_RELAXED,
                                               __HIP_MEMORY_SCOPE_AGENT);
        }

        f32x4 acc[6] = {};
        #pragma unroll
        for (int kc = 0; kc < 4; ++kc) {
            union { unsigned long long q[2]; bf16x8 v; } u;
            u.q[0] = hv[2 * kc]; u.q[1] = hv[2 * kc + 1];
            #pragma unroll
            for (int nt = 0; nt < 6; ++nt)
                acc[nt] = __builtin_amdgcn_mfma_f32_16x16x32_bf16(u.v, wf[kc][nt], acc[nt], 0, 0, 0);
        }

        #pragma unroll
        for (int nt = 0; nt < 6; ++nt)
            #pragma unroll
            for (int e = 0; e < 4; ++e)
                part[wave][nt][e][lane] = acc[nt][e];
        __syncthreads();

        float hr = 0.f, hz = 0.f, hn = 0.f;
        #pragma unroll
        for (int w = 0; w < 8; ++w) {
            hr += part[w][0 + nt_r][e_r][lp];
            hz += part[w][2 + nt_r][e_r][lp];
            hn += part[w][4 + nt_r][e_r][lp];
        }

        float r  = __builtin_amdgcn_rcpf(1.f + __expf(-(ir + hr)));
        float z  = __builtin_amdgcn_rcpf(1.f + __expf(-(iz + hz)));
        float e2 = __expf(2.f * (inn + r * hn));
        float n  = 1.f - 2.f * __builtin_amdgcn_rcpf(e2 + 1.f);
        float hnew = (1.f - z) * n + z * hreg;
        hreg = hnew;

        unsigned short myb = f2b(hnew);
        unsigned pv = (unsigned)__shfl_xor((int)(unsigned)myb, 1);
        if (!(j_l & 1)) {
            unsigned val = ((unsigned)myb) | (pv << 16);
            __hip_atomic_store((unsigned*)((char*)wslab + prod_off), val,
                               __ATOMIC_RELAXED, __HIP_MEMORY_SCOPE_AGENT);
        }

        asm volatile("s_waitcnt vmcnt(0)" ::: "memory");
        __syncthreads();
        if (t == 0)
            __hip_atomic_store(&flags[((group << 5) | jb) << 4], s + 1,
                               __ATOMIC_RELAXED, __HIP_MEMORY_SCOPE_AGENT);

        out[((size_t)b_g * SS + s) * HH + j_g] = hnew;
    }

    out[(size_t)BB * SS * HH + (size_t)b_g * HH + j_g] = hreg;
}

// ---------------------------------------------------------------------------
// Host launcher
// ---------------------------------------------------------------------------
extern "C" void kernel_launch(void* const* d_in, const int* in_sizes, int n_in,
                              void* d_out, int out_size, void* d_ws, size_t ws_size,
                              hipStream_t stream)
{
    const float* x   = (const float*)d_in[0];
    const float* h0  = (const float*)d_in[1];
    const float* Wih = (const float*)d_in[2];
    const float* Whh = (const float*)d_in[3];
    const float* bih = (const float*)d_in[4];
    float* out = (float*)d_out;

    char* ws = (char*)d_ws;
    unsigned short* h16 = (unsigned short*)ws;               // 2 x 128KiB parity bufs
    int* flags          = (int*)(ws + 262144);               // counters + chunk ctrs
    void* gi            = (void*)(ws + (1 << 20));           // 1 MiB offset

    const size_t gi32_bytes = (size_t)BB * SS * G3 * 4;      // 768 MiB
    const size_t gi16_bytes = gi32_bytes / 2;                // 384 MiB
    const size_t xb_off   = (size_t)(1 << 20) + gi32_bytes;
    const size_t wb_off   = xb_off + (size_t)BB * SS * II * 2;
    const size_t need_new = wb_off + (size_t)G3 * II * 2;

    const bool use_new = ws_size >= need_new;
    const bool use_f32 = !use_new && ws_size >= ((size_t)(1 << 20) + gi32_bytes);
    const bool use_b16 = !use_new && !use_f32 &&
                         ws_size >= ((size_t)(1 << 20) + gi16_bytes);
    if (!use_new && !use_f32 && !use_b16) return;

    gru_init<<<dim3(256), dim3(256), 0, stream>>>(h0, h16, flags);

    if (use_new) {
        unsigned short* xb = (unsigned short*)(ws + xb_off);
        unsigned short* wb = (unsigned short*)(ws + wb_off);
        conv_b16<<<dim3(68608), dim3(256), 0, stream>>>(x, Wih, xb, wb);
        unsigned short* gi16_p = (unsigned short*)gi;
        const unsigned short* xb_c = xb;
        const unsigned short* wb_c = wb;
        const float* bih_c = bih;
        const float* Whh_c = Whh;
        const float* h0_c = h0;
        unsigned short* h16_c = h16;
        int* flags_c = flags;
        float* out_c = out;
        void* args[] = { (void*)&gi16_p, (void*)&xb_c, (void*)&wb_c, (void*)&bih_c,
                         (void*)&Whh_c, (void*)&h0_c, (void*)&h16_c,
                         (void*)&flags_c, (void*)&out_c };
        hipLaunchCooperativeKernel((const void*)&gru_fused, dim3(256), dim3(512),
                                   args, 0, stream);
    } else {
        const void* gi_c = gi;
        const float* Whh_c = Whh;
        const float* h0_c = h0;
        unsigned short* h16_c = h16;
        int* flags_c = flags;
        float* out_c = out;
        void* args[] = { (void*)&gi_c, (void*)&Whh_c, (void*)&h0_c,
                         (void*)&h16_c, (void*)&flags_c, (void*)&out_c };
        if (use_f32) {
            gi_gemm<0><<<dim3(24, 512), dim3(256), 0, stream>>>(x, Wih, bih, gi);
            hipLaunchCooperativeKernel((const void*)&gru_scan<0>, dim3(128), dim3(512),
                                       args, 0, stream);
        } else {
            gi_gemm<1><<<dim3(24, 512), dim3(256), 0, stream>>>(x, Wih, bih, gi);
            hipLaunchCooperativeKernel((const void*)&gru_scan<1>, dim3(128), dim3(512),
                                       args, 0, stream);
        }
    }
}

// Round 16
// 3058.148 us; speedup vs baseline: 1.5141x; 1.5141x over previous
//
#include <hip/hip_runtime.h>
#include <hip/hip_bf16.h>
#include <cstdint>
#include <cstddef>

// Problem sizes (fixed)
#define BB 64
#define SS 1024
#define II 1024
#define HH 1024
#define G3 3072   // 3*HH

typedef float  f32x4  __attribute__((ext_vector_type(4)));
typedef short  bf16x8 __attribute__((ext_vector_type(8)));

__device__ __forceinline__ unsigned short f2b(float f) {
    unsigned u = __float_as_uint(f);
    u += 0x7FFFu + ((u >> 16) & 1u);   // RNE
    return (unsigned short)(u >> 16);
}
__device__ __forceinline__ float b2f(unsigned short s) {
    return __uint_as_float(((unsigned)s) << 16);
}

// ---------------------------------------------------------------------------
// Kernel 0: bf16 prepass — xb = bf16(x), wb = bf16(W_ih). One pass, HBM-bound.
// ---------------------------------------------------------------------------
__global__ __launch_bounds__(256)
void conv_b16(const float* __restrict__ x, const float* __restrict__ w,
              unsigned short* __restrict__ xb, unsigned short* __restrict__ wb)
{
    const size_t XN = (size_t)BB * SS * II;     // 67108864
    const size_t WN = (size_t)G3 * II;          // 3145728
    size_t i = ((size_t)blockIdx.x * 256 + threadIdx.x) * 4;
    if (i < XN) {
        float4 v = *reinterpret_cast<const float4*>(x + i);
        uint2 p;
        p.x = (unsigned)f2b(v.x) | ((unsigned)f2b(v.y) << 16);
        p.y = (unsigned)f2b(v.z) | ((unsigned)f2b(v.w) << 16);
        *reinterpret_cast<uint2*>(xb + i) = p;
    } else {
        size_t j = i - XN;
        if (j < WN) {
            float4 v = *reinterpret_cast<const float4*>(w + j);
            uint2 p;
            p.x = (unsigned)f2b(v.x) | ((unsigned)f2b(v.y) << 16);
            p.y = (unsigned)f2b(v.z) | ((unsigned)f2b(v.w) << 16);
            *reinterpret_cast<uint2*>(wb + j) = p;
        }
    }
}

// ---------------------------------------------------------------------------
// Kernel 2: init  (reset flags + chunk counters, h16[buf0] = bf16(h0))
// ---------------------------------------------------------------------------
__global__ __launch_bounds__(256)
void gru_init(const float* __restrict__ h0, unsigned short* __restrict__ h16,
              int* __restrict__ flags)
{
    int i = blockIdx.x * 256 + threadIdx.x;   // i = b*1024 + j, 65536 total
    int b = i >> 10, j = i & 1023;
    int dst = (b >> 4) * 16384 + (j >> 3) * 128 + (b & 15) * 8 + (j & 7);
    h16[dst] = f2b(h0[i]);
    if (i < 2304) flags[i] = 0;   // 128 h-flags @ 64B stride + 8 chunk counters
}

// ---------------------------------------------------------------------------
// One 128x128 GEMM tile job: gi16[m0..m0+128, n0..n0+128) = xb @ wb^T + bias,
// written as packed bf16 pairs via sc1 (agent) stores. Called by all 512
// threads of a block; uses As/Bs (32KB) of smem.
// ---------------------------------------------------------------------------
__device__ __forceinline__ void gemm_tile(
    const unsigned short* __restrict__ XB, const unsigned short* __restrict__ WB,
    const float* __restrict__ bias, unsigned short* __restrict__ gi16,
    short* As, short* Bs, int m0, int n0, int t, int lane, int wave)
{
    const int lr = lane >> 3;             // 0..7
    const int lc = (lane & 7) * 8;        // bf16 col
    const int mb = (wave & 1) * 64;
    const int nb = (wave >> 1) * 32;

    f32x4 acc[4][2] = {};
    for (int k0 = 0; k0 < II; k0 += 64) {
        __syncthreads();
        #pragma unroll
        for (int p = 0; p < 2; ++p) {
            int sg = p * 8 + wave;        // 0..15, wave-uniform
            const unsigned short* ga = XB + (size_t)(m0 + sg * 8 + lr) * II + k0 + lc;
            const unsigned short* gb = WB + (size_t)(n0 + sg * 8 + lr) * II + k0 + lc;
            __builtin_amdgcn_global_load_lds(
                (const __attribute__((address_space(1))) void*)ga,
                (__attribute__((address_space(3))) void*)(As + sg * 512), 16, 0, 0);
            __builtin_amdgcn_global_load_lds(
                (const __attribute__((address_space(1))) void*)gb,
                (__attribute__((address_space(3))) void*)(Bs + sg * 512), 16, 0, 0);
        }
        __syncthreads();
        #pragma unroll
        for (int ks = 0; ks < 2; ++ks) {
            bf16x8 af[4], bf[2];
            #pragma unroll
            for (int i = 0; i < 4; ++i)
                af[i] = *reinterpret_cast<const bf16x8*>(
                    As + (mb + i * 16 + (lane & 15)) * 64 + ks * 32 + (lane >> 4) * 8);
            #pragma unroll
            for (int i = 0; i < 2; ++i)
                bf[i] = *reinterpret_cast<const bf16x8*>(
                    Bs + (nb + i * 16 + (lane & 15)) * 64 + ks * 32 + (lane >> 4) * 8);
            #pragma unroll
            for (int mi = 0; mi < 4; ++mi)
                #pragma unroll
                for (int ni = 0; ni < 2; ++ni)
                    acc[mi][ni] = __builtin_amdgcn_mfma_f32_16x16x32_bf16(
                        af[mi], bf[ni], acc[mi][ni], 0, 0, 0);
        }
    }
    // epilogue: bias add, bf16 pack across lane pairs, sc1 u32 stores
    #pragma unroll
    for (int ni = 0; ni < 2; ++ni) {
        int ncol = n0 + nb + ni * 16 + (lane & 15);
        float bv = bias[ncol];
        #pragma unroll
        for (int mi = 0; mi < 4; ++mi) {
            int mrow = m0 + mb + mi * 16 + ((lane >> 4) << 2);
            #pragma unroll
            for (int e = 0; e < 4; ++e) {
                float v = acc[mi][ni][e] + bv;
                unsigned short hb = f2b(v);
                unsigned pv = (unsigned)__shfl_xor((int)(unsigned)hb, 1);
                if (!(lane & 1)) {
                    unsigned word = (unsigned)hb | (pv << 16);
                    __hip_atomic_store(
                        (unsigned*)(gi16 + (size_t)(mrow + e) * G3 + ncol),
                        word, __ATOMIC_RELAXED, __HIP_MEMORY_SCOPE_AGENT);
                }
            }
        }
    }
}

// ---------------------------------------------------------------------------
// Kernel F: FUSED producer-consumer. Cooperative 256 blocks x 512 threads.
// Phase 0 (ALL blocks): 6 chunk-0 tiles each (256*6 = 1536 = whole chunk 0)
//   -> done[0] += 1 (target 256). Halves the priming delay.
// Then bid<128: scan role (r14 datapath + 2-deep pipelined poll);
//      bid>=128: worker role — chunks 1..7, 12 jobs each -> done[c] += 1.
// ---------------------------------------------------------------------------
__global__ __launch_bounds__(512, 1)
void gru_fused(unsigned short* __restrict__ gi16,
               const unsigned short* __restrict__ XB,
               const unsigned short* __restrict__ WB, const float* __restrict__ bias,
               const float* __restrict__ Whh, const float* __restrict__ h0,
               unsigned short* __restrict__ h16, int* __restrict__ flags,
               float* __restrict__ out)
{
    __shared__ char smem[52224];
    const int t    = threadIdx.x;
    const int lane = t & 63;
    const int wave = t >> 6;          // 0..7
    const int bid  = blockIdx.x;

    short* As = (short*)smem;
    short* Bs = (short*)(smem + 16384);

    // ---- phase 0: all 256 blocks produce chunk 0 (tiles bid*6 .. bid*6+5) ----
    #pragma unroll 1
    for (int q = 0; q < 6; ++q) {
        int tile = bid * 6 + q;          // 0..1535
        int b = tile / 24, n = tile % 24;
        gemm_tile(XB, WB, bias, gi16, As, Bs, b * 1024, n * 128, t, lane, wave);
    }
    asm volatile("s_waitcnt vmcnt(0)" ::: "memory");
    __syncthreads();                     // all sc1 stores drained, smem free
    if (t == 0)
        __hip_atomic_fetch_add(&flags[2048], 1,
                               __ATOMIC_RELAXED, __HIP_MEMORY_SCOPE_AGENT);

    if (bid >= 128) {
        // =================== worker role: chunks 1..7 ===================
        const int wkr = bid - 128;
        #pragma unroll 1
        for (int jj = 0; jj < 84; ++jj) {
            int c   = 1 + jj / 12;
            int idx = (jj % 12) * 128 + wkr;     // 0..1535 within chunk
            int b = idx / 24, n = idx % 24;
            gemm_tile(XB, WB, bias, gi16, As, Bs,
                      b * 1024 + c * 128, n * 128, t, lane, wave);
            if ((jj % 12) == 11) {
                asm volatile("s_waitcnt vmcnt(0)" ::: "memory");
                __syncthreads();
                if (t == 0)
                    __hip_atomic_fetch_add(&flags[2048 + (c << 4)], 1,
                                           __ATOMIC_RELAXED, __HIP_MEMORY_SCOPE_AGENT);
            }
        }
        return;
    }

    // =================== scan role (proven r14 datapath) ===================
    auto part = reinterpret_cast<float(*)[6][4][68]>(smem);  // [8][6][4][68]

    const int group = bid & 3;
    const int jb    = bid >> 2;        // 0..31

    bf16x8 wf[4][6];
    #pragma unroll
    for (int kc = 0; kc < 4; ++kc) {
        #pragma unroll
        for (int nt = 0; nt < 6; ++nt) {
            int rowg = (nt >> 1) * HH + jb * 32 + (nt & 1) * 16 + (lane & 15);
            int k    = wave * 128 + kc * 32 + ((lane >> 4) << 3);
            const float4* src = reinterpret_cast<const float4*>(Whh + (size_t)rowg * HH + k);
            float4 f0 = src[0], f1 = src[1];
            bf16x8 w;
            w[0] = (short)f2b(f0.x); w[1] = (short)f2b(f0.y);
            w[2] = (short)f2b(f0.z); w[3] = (short)f2b(f0.w);
            w[4] = (short)f2b(f1.x); w[5] = (short)f2b(f1.y);
            w[6] = (short)f2b(f1.z); w[7] = (short)f2b(f1.w);
            wf[kc][nt] = w;
        }
    }

    const int b_l = t >> 5;
    const int j_l = t & 31;
    const int b_g = (group << 4) + b_l;
    const int j_g = (jb << 5) + j_l;
    float hreg = h0[b_g * HH + j_g];

    const int frag_base = (wave * 16 + (lane >> 4)) * 256 + ((lane & 15) << 4);
    const int prod_off  = ((j_g >> 3) << 8) + (b_l << 4) + ((j_g & 7) << 1);

    const int nt_r = j_l >> 4;
    const int lp   = ((b_l >> 2) << 4) | (j_l & 15);
    const int e_r  = b_l & 3;

    const int poll_fi = ((group << 5) | (wave << 2) | (lane & 3)) << 4;
    const int jeven = j_g & ~1;
    const int jsel  = (j_g & 1) << 4;   // 0 or 16 bit shift

    for (int s = 0; s < SS; ++s) {
        // chunk gate: gi chunk (s>>7) fully produced (chunk0 target 256)
        if ((s & 127) == 0) {
            const int target = (s == 0) ? 256 : 128;
            if (t == 0) {
                while (__hip_atomic_load(&flags[2048 + ((s >> 7) << 4)],
                                         __ATOMIC_RELAXED, __HIP_MEMORY_SCOPE_AGENT) < target)
                    __builtin_amdgcn_s_sleep(2);
            }
            __syncthreads();
        }

        const int p = s & 1;
        const char* rslab = (const char*)(h16 + (size_t)p * 65536 + group * 16384);
        unsigned short* wslab = h16 + (size_t)(p ^ 1) * 65536 + group * 16384;

        // prefetch gi (bf16 pairs, sc1: fresh across XCDs)
        size_t gib = ((size_t)b_g * SS + s) * G3;
        unsigned wr = __hip_atomic_load((const unsigned*)(gi16 + gib + jeven),
                                        __ATOMIC_RELAXED, __HIP_MEMORY_SCOPE_AGENT);
        unsigned wz = __hip_atomic_load((const unsigned*)(gi16 + gib + HH + jeven),
                                        __ATOMIC_RELAXED, __HIP_MEMORY_SCOPE_AGENT);
        unsigned wn = __hip_atomic_load((const unsigned*)(gi16 + gib + 2 * HH + jeven),
                                        __ATOMIC_RELAXED, __HIP_MEMORY_SCOPE_AGENT);
        float ir  = b2f((unsigned short)(wr >> jsel));
        float iz  = b2f((unsigned short)(wz >> jsel));
        float inn = b2f((unsigned short)(wn >> jsel));

        // fine poll (2-deep pipelined): keep two loads in flight so the check
        // of one overlaps the fabric RT of the next — halves detect latency.
        // Stale/extra reads are harmless (flags monotone).
        if (s > 0) {
            int a = __hip_atomic_load(&flags[poll_fi], __ATOMIC_RELAXED,
                                      __HIP_MEMORY_SCOPE_AGENT);
            while (true) {
                int b2v = __hip_atomic_load(&flags[poll_fi], __ATOMIC_RELAXED,
                                            __HIP_MEMORY_SCOPE_AGENT);
                if (__all(a >= s)) break;
                a = __hip_atomic_load(&flags[poll_fi], __ATOMIC_RELAXED,
                                      __HIP_MEMORY_SCOPE_AGENT);
                if (__all(b2v >= s)) break;
            }
            asm volatile("" ::: "memory");
        }

        unsigned long long hv[8];
        #pragma unroll
        for (int kc = 0; kc < 4; ++kc) {
            const unsigned long long* q =
                (const unsigned long long*)(rslab + frag_base + kc * 1024);
            hv[2 * kc]     = __hip_atomic_load(q,     __ATOMIC_RELAXED,
                                               __HIP_MEMORY_SCOPE_AGENT);
            hv[2 * kc + 1] = __hip_atomic_load(q + 1, __ATOMIC_RELAXED,
                                               __HIP_MEMORY_SCOPE_AGENT);
        }

        f32x4 acc[6] = {};
        #pragma unroll
        for (int kc = 0; kc < 4; ++kc) {
            union { unsigned long long q[2]; bf16x8 v; } u;
            u.q[0] = hv[2 * kc]; u.q[1] = hv[2 * kc + 1];
            #pragma unroll
            for (int nt = 0; nt < 6; ++nt)
                acc[nt] = __builtin_amdgcn_mfma_f32_16x16x32_bf16(u.v, wf[kc][nt], acc[nt], 0, 0, 0);
        }

        #pragma unroll
        for (int nt = 0; nt < 6; ++nt)
            #pragma unroll
            for (int e = 0; e < 4; ++e)
                part[wave][nt][e][lane] = acc[nt][e];
        __syncthreads();   // bar1

        float hr = 0.f, hz = 0.f, hn = 0.f;
        #pragma unroll
        for (int w = 0; w < 8; ++w) {
            hr += part[w][0 + nt_r][e_r][lp];
            hz += part[w][2 + nt_r][e_r][lp];
            hn += part[w][4 + nt_r][e_r][lp];
        }

        float r  = __builtin_amdgcn_rcpf(1.f + __expf(-(ir + hr)));
        float z  = __builtin_amdgcn_rcpf(1.f + __expf(-(iz + hz)));
        float e2 = __expf(2.f * (inn + r * hn));
        float n  = 1.f - 2.f * __builtin_amdgcn_rcpf(e2 + 1.f);
        float hnew = (1.f - z) * n + z * hreg;
        hreg = hnew;

        unsigned short myb = f2b(hnew);
        unsigned pv = (unsigned)__shfl_xor((int)(unsigned)myb, 1);
        if (!(j_l & 1)) {
            unsigned val = ((unsigned)myb) | (pv << 16);
            __hip_atomic_store((unsigned*)((char*)wslab + prod_off), val,
                               __ATOMIC_RELAXED, __HIP_MEMORY_SCOPE_AGENT);
        }

        asm volatile("s_waitcnt vmcnt(0)" ::: "memory");
        __syncthreads();   // bar2
        if (t == 0)
            __hip_atomic_store(&flags[((group << 5) | jb) << 4], s + 1,
                               __ATOMIC_RELAXED, __HIP_MEMORY_SCOPE_AGENT);

        out[((size_t)b_g * SS + s) * HH + j_g] = hnew;
    }

    out[(size_t)BB * SS * HH + (size_t)b_g * HH + j_g] = hreg;
}

// ---------------------------------------------------------------------------
// Fallback (ws too small for xb/wb): old serial inline-convert GEMM + scan.
// ---------------------------------------------------------------------------
template<int GI_BF16>
__global__ __launch_bounds__(256)
void gi_gemm(const float* __restrict__ X, const float* __restrict__ W,
             const float* __restrict__ bias, void* __restrict__ gi_out)
{
    __shared__ short As[128][40];
    __shared__ short Bs[128][40];

    const int t    = threadIdx.x;
    const int lane = t & 63;
    const int wave = t >> 6;
    const int m0   = blockIdx.y * 128;
    const int n0   = blockIdx.x * 128;

    f32x4 acc[4][4] = {};

    for (int k0 = 0; k0 < II; k0 += 32) {
        __syncthreads();
        #pragma unroll
        for (int q = 0; q < 2; ++q) {
            int row = (t >> 2) + 64 * q;
            int col = (t & 3) * 8;
            const float4* ap = reinterpret_cast<const float4*>(X + (size_t)(m0 + row) * II + k0 + col);
            const float4* bp = reinterpret_cast<const float4*>(W + (size_t)(n0 + row) * II + k0 + col);
            float4 a0 = ap[0], a1 = ap[1];
            float4 b0 = bp[0], b1 = bp[1];
            bf16x8 av, bv;
            av[0] = (short)f2b(a0.x); av[1] = (short)f2b(a0.y);
            av[2] = (short)f2b(a0.z); av[3] = (short)f2b(a0.w);
            av[4] = (short)f2b(a1.x); av[5] = (short)f2b(a1.y);
            av[6] = (short)f2b(a1.z); av[7] = (short)f2b(a1.w);
            bv[0] = (short)f2b(b0.x); bv[1] = (short)f2b(b0.y);
            bv[2] = (short)f2b(b0.z); bv[3] = (short)f2b(b0.w);
            bv[4] = (short)f2b(b1.x); bv[5] = (short)f2b(b1.y);
            bv[6] = (short)f2b(b1.z); bv[7] = (short)f2b(b1.w);
            *reinterpret_cast<bf16x8*>(&As[row][col]) = av;
            *reinterpret_cast<bf16x8*>(&Bs[row][col]) = bv;
        }
        __syncthreads();

        const int mb = (wave & 1) * 64;
        const int nb = (wave >> 1) * 64;
        bf16x8 af[4], bf[4];
        #pragma unroll
        for (int i = 0; i < 4; ++i) {
            af[i] = *reinterpret_cast<const bf16x8*>(&As[mb + i * 16 + (lane & 15)][(lane >> 4) * 8]);
            bf[i] = *reinterpret_cast<const bf16x8*>(&Bs[nb + i * 16 + (lane & 15)][(lane >> 4) * 8]);
        }
        #pragma unroll
        for (int mi = 0; mi < 4; ++mi)
            #pragma unroll
            for (int ni = 0; ni < 4; ++ni)
                acc[mi][ni] = __builtin_amdgcn_mfma_f32_16x16x32_bf16(af[mi], bf[ni], acc[mi][ni], 0, 0, 0);
    }

    const int mb = (wave & 1) * 64;
    const int nb = (wave >> 1) * 64;
    #pragma unroll
    for (int ni = 0; ni < 4; ++ni) {
        int ncol = n0 + nb + ni * 16 + (lane & 15);
        float bv = bias[ncol];
        #pragma unroll
        for (int mi = 0; mi < 4; ++mi) {
            int mrow = m0 + mb + mi * 16 + ((lane >> 4) << 2);
            #pragma unroll
            for (int e = 0; e < 4; ++e) {
                float v = acc[mi][ni][e] + bv;
                size_t idx = (size_t)(mrow + e) * G3 + ncol;
                if (GI_BF16) ((unsigned short*)gi_out)[idx] = f2b(v);
                else         ((float*)gi_out)[idx] = v;
            }
        }
    }
}

template<int GI_BF16>
__global__ __launch_bounds__(512, 1)
void gru_scan(const void* __restrict__ gi_v, const float* __restrict__ Whh,
              const float* __restrict__ h0, unsigned short* __restrict__ h16,
              int* __restrict__ flags, float* __restrict__ out)
{
    const int t     = threadIdx.x;
    const int lane  = t & 63;
    const int wave  = t >> 6;
    const int bid   = blockIdx.x;
    const int group = bid & 3;
    const int jb    = bid >> 2;

    __shared__ float part[8][6][4][68];

    bf16x8 wf[4][6];
    #pragma unroll
    for (int kc = 0; kc < 4; ++kc) {
        #pragma unroll
        for (int nt = 0; nt < 6; ++nt) {
            int rowg = (nt >> 1) * HH + jb * 32 + (nt & 1) * 16 + (lane & 15);
            int k    = wave * 128 + kc * 32 + ((lane >> 4) << 3);
            const float4* src = reinterpret_cast<const float4*>(Whh + (size_t)rowg * HH + k);
            float4 f0 = src[0], f1 = src[1];
            bf16x8 w;
            w[0] = (short)f2b(f0.x); w[1] = (short)f2b(f0.y);
            w[2] = (short)f2b(f0.z); w[3] = (short)f2b(f0.w);
            w[4] = (short)f2b(f1.x); w[5] = (short)f2b(f1.y);
            w[6] = (short)f2b(f1.z); w[7] = (short)f2b(f1.w);
            wf[kc][nt] = w;
        }
    }

    const int b_l = t >> 5;
    const int j_l = t & 31;
    const int b_g = (group << 4) + b_l;
    const int j_g = (jb << 5) + j_l;
    float hreg = h0[b_g * HH + j_g];

    const int frag_base = (wave * 16 + (lane >> 4)) * 256 + ((lane & 15) << 4);
    const int prod_off  = ((j_g >> 3) << 8) + (b_l << 4) + ((j_g & 7) << 1);

    const int nt_r = j_l >> 4;
    const int lp   = ((b_l >> 2) << 4) | (j_l & 15);
    const int e_r  = b_l & 3;

    const int poll_fi = ((group << 5) | (wave << 2) | (lane & 3)) << 4;

    for (int s = 0; s < SS; ++s) {
        const int p = s & 1;
        const char* rslab = (const char*)(h16 + (size_t)p * 65536 + group * 16384);
        unsigned short* wslab = h16 + (size_t)(p ^ 1) * 65536 + group * 16384;

        size_t gib = ((size_t)b_g * SS + s) * G3;
        float ir, iz, inn;
        if (GI_BF16) {
            const unsigned short* g16 = (const unsigned short*)gi_v;
            ir  = b2f(g16[gib + j_g]);
            iz  = b2f(g16[gib + HH + j_g]);
            inn = b2f(g16[gib + 2 * HH + j_g]);
        } else {
            const float* g32 = (const float*)gi_v;
            ir  = g32[gib + j_g];
            iz  = g32[gib + HH + j_g];
            inn = g32[gib + 2 * HH + j_g];
        }

        if (s > 0) {
            while (true) {
                int v = __hip_atomic_load(&flags[poll_fi], __ATOMIC_RELAXED,
                                          __HIP_MEMORY_SCOPE_AGENT);
                if (__all(v >= s)) break;
            }
            asm volatile("" ::: "memory");
        }

        unsigned long long hv[8];
        #pragma unroll
        for (int kc = 0; kc < 4; ++kc) {
            const unsigned long long* q =
                (const unsigned long long*)(rslab + frag_base + kc * 1024);
            hv[2 * kc]     = __hip_atomic_load(q,     __ATOMIC_RELAXED,
                                               __HIP_MEMORY_SCOPE_AGENT);
            hv[2 * kc + 1] = __hip_atomic_load(q + 1, __ATOMIC_RELAXED,
                                               __HIP_MEMORY_SCOPE_AGENT);
        }

        f32x4 acc[6] = {};
        #pragma unroll
        for (int kc = 0; kc < 4; ++kc) {
            union { unsigned long long q[2]; bf16x8 v; } u;
            u.q[0] = hv[2 * kc]; u.q[1] = hv[2 * kc + 1];
            #pragma unroll
            for (int nt = 0; nt < 6; ++nt)
                acc[nt] = __builtin_amdgcn_mfma_f32_16x16x32_bf16(u.v, wf[kc][nt], acc[nt], 0, 0, 0);
        }

        #pragma unroll
        for (int nt = 0; nt < 6; ++nt)
            #pragma unroll
            for (int e = 0; e < 4; ++e)
                part[wave][nt][e][lane] = acc[nt][e];
        __syncthreads();

        float hr = 0.f, hz = 0.f, hn = 0.f;
        #pragma unroll
        for (int w = 0; w < 8; ++w) {
            hr += part[w][0 + nt_r][e_r][lp];
            hz += part[w][2 + nt_r][e_r][lp];
            hn += part[w][4 + nt_r][e_r][lp];
        }

        float r  = __builtin_amdgcn_rcpf(1.f + __expf(-(ir + hr)));
        float z  = __builtin_amdgcn_rcpf(1.f + __expf(-(iz + hz)));
        float e2 = __expf(2.f * (inn + r * hn));
        float n  = 1.f - 2.f * __builtin_amdgcn_rcpf(e2 + 1.f);
        float hnew = (1.f - z) * n + z * hreg;
        hreg = hnew;

        unsigned short myb = f2b(hnew);
        unsigned pv = (unsigned)__shfl_xor((int)(unsigned)myb, 1);
        if (!(j_l & 1)) {
            unsigned val = ((unsigned)myb) | (pv << 16);
            __hip_atomic_store((unsigned*)((char*)wslab + prod_off), val,
                               __ATOMIC_RELAXED, __HIP_MEMORY_SCOPE_AGENT);
        }

        asm volatile("s_waitcnt vmcnt(0)" ::: "memory");
        __syncthreads();
        if (t == 0)
            __hip_atomic_store(&flags[((group << 5) | jb) << 4], s + 1,
                               __ATOMIC_RELAXED, __HIP_MEMORY_SCOPE_AGENT);

        out[((size_t)b_g * SS + s) * HH + j_g] = hnew;
    }

    out[(size_t)BB * SS * HH + (size_t)b_g * HH + j_g] = hreg;
}

// ---------------------------------------------------------------------------
// Host launcher
// ---------------------------------------------------------------------------
extern "C" void kernel_launch(void* const* d_in, const int* in_sizes, int n_in,
                              void* d_out, int out_size, void* d_ws, size_t ws_size,
                              hipStream_t stream)
{
    const float* x   = (const float*)d_in[0];
    const float* h0  = (const float*)d_in[1];
    const float* Wih = (const float*)d_in[2];
    const float* Whh = (const float*)d_in[3];
    const float* bih = (const float*)d_in[4];
    float* out = (float*)d_out;

    char* ws = (char*)d_ws;
    unsigned short* h16 = (unsigned short*)ws;               // 2 x 128KiB parity bufs
    int* flags          = (int*)(ws + 262144);               // h-flags + chunk ctrs
    void* gi            = (void*)(ws + (1 << 20));           // 1 MiB offset

    const size_t gi32_bytes = (size_t)BB * SS * G3 * 4;      // 768 MiB
    const size_t gi16_bytes = gi32_bytes / 2;                // 384 MiB
    const size_t xb_off   = (size_t)(1 << 20) + gi32_bytes;
    const size_t wb_off   = xb_off + (size_t)BB * SS * II * 2;
    const size_t need_new = wb_off + (size_t)G3 * II * 2;

    const bool use_new = ws_size >= need_new;
    const bool use_f32 = !use_new && ws_size >= ((size_t)(1 << 20) + gi32_bytes);
    const bool use_b16 = !use_new && !use_f32 &&
                         ws_size >= ((size_t)(1 << 20) + gi16_bytes);
    if (!use_new && !use_f32 && !use_b16) return;

    gru_init<<<dim3(256), dim3(256), 0, stream>>>(h0, h16, flags);

    if (use_new) {
        unsigned short* xb = (unsigned short*)(ws + xb_off);
        unsigned short* wb = (unsigned short*)(ws + wb_off);
        conv_b16<<<dim3(68608), dim3(256), 0, stream>>>(x, Wih, xb, wb);
        unsigned short* gi16_p = (unsigned short*)gi;
        const unsigned short* xb_c = xb;
        const unsigned short* wb_c = wb;
        const float* bih_c = bih;
        const float* Whh_c = Whh;
        const float* h0_c = h0;
        unsigned short* h16_c = h16;
        int* flags_c = flags;
        float* out_c = out;
        void* args[] = { (void*)&gi16_p, (void*)&xb_c, (void*)&wb_c, (void*)&bih_c,
                         (void*)&Whh_c, (void*)&h0_c, (void*)&h16_c,
                         (void*)&flags_c, (void*)&out_c };
        hipLaunchCooperativeKernel((const void*)&gru_fused, dim3(256), dim3(512),
                                   args, 0, stream);
    } else {
        const void* gi_c = gi;
        const float* Whh_c = Whh;
        const float* h0_c = h0;
        unsigned short* h16_c = h16;
        int* flags_c = flags;
        float* out_c = out;
        void* args[] = { (void*)&gi_c, (void*)&Whh_c, (void*)&h0_c,
                         (void*)&h16_c, (void*)&flags_c, (void*)&out_c };
        if (use_f32) {
            gi_gemm<0><<<dim3(24, 512), dim3(256), 0, stream>>>(x, Wih, bih, gi);
            hipLaunchCooperativeKernel((const void*)&gru_scan<0>, dim3(128), dim3(512),
                                       args, 0, stream);
        } else {
            gi_gemm<1><<<dim3(24, 512), dim3(256), 0, stream>>>(x, Wih, bih, gi);
            hipLaunchCooperativeKernel((const void*)&gru_scan<1>, dim3(128), dim3(512),
                                       args, 0, stream);
        }
    }
}

// Round 17
// 2984.320 us; speedup vs baseline: 1.5516x; 1.0247x over previous
//
#include <hip/hip_runtime.h>
#include <hip/hip_bf16.h>
#include <cstdint>
#include <cstddef>

// Problem sizes (fixed)
#define BB 64
#define SS 1024
#define II 1024
#define HH 1024
#define G3 3072   // 3*HH

typedef float  f32x4  __attribute__((ext_vector_type(4)));
typedef short  bf16x8 __attribute__((ext_vector_type(8)));

__device__ __forceinline__ unsigned short f2b(float f) {
    unsigned u = __float_as_uint(f);
    u += 0x7FFFu + ((u >> 16) & 1u);   // RNE
    return (unsigned short)(u >> 16);
}
__device__ __forceinline__ float b2f(unsigned short s) {
    return __uint_as_float(((unsigned)s) << 16);
}

// ---------------------------------------------------------------------------
// Kernel 0: bf16 prepass — xb = bf16(x), wb = bf16(W_ih). One pass, HBM-bound.
// ---------------------------------------------------------------------------
__global__ __launch_bounds__(256)
void conv_b16(const float* __restrict__ x, const float* __restrict__ w,
              unsigned short* __restrict__ xb, unsigned short* __restrict__ wb)
{
    const size_t XN = (size_t)BB * SS * II;     // 67108864
    const size_t WN = (size_t)G3 * II;          // 3145728
    size_t i = ((size_t)blockIdx.x * 256 + threadIdx.x) * 4;
    if (i < XN) {
        float4 v = *reinterpret_cast<const float4*>(x + i);
        uint2 p;
        p.x = (unsigned)f2b(v.x) | ((unsigned)f2b(v.y) << 16);
        p.y = (unsigned)f2b(v.z) | ((unsigned)f2b(v.w) << 16);
        *reinterpret_cast<uint2*>(xb + i) = p;
    } else {
        size_t j = i - XN;
        if (j < WN) {
            float4 v = *reinterpret_cast<const float4*>(w + j);
            uint2 p;
            p.x = (unsigned)f2b(v.x) | ((unsigned)f2b(v.y) << 16);
            p.y = (unsigned)f2b(v.z) | ((unsigned)f2b(v.w) << 16);
            *reinterpret_cast<uint2*>(wb + j) = p;
        }
    }
}

// ---------------------------------------------------------------------------
// Kernel 2: init  (reset flags + chunk counters, h16[buf0] = bf16(h0))
// ---------------------------------------------------------------------------
__global__ __launch_bounds__(256)
void gru_init(const float* __restrict__ h0, unsigned short* __restrict__ h16,
              int* __restrict__ flags)
{
    int i = blockIdx.x * 256 + threadIdx.x;   // i = b*1024 + j, 65536 total
    int b = i >> 10, j = i & 1023;
    int dst = (b >> 4) * 16384 + (j >> 3) * 128 + (b & 15) * 8 + (j & 7);
    h16[dst] = f2b(h0[i]);
    if (i < 2304) flags[i] = 0;   // 128 h-flags @ 64B stride + 8 chunk counters
}

// ---------------------------------------------------------------------------
// One 128x128 GEMM tile job: gi16[m0..m0+128, n0..n0+128) = xb @ wb^T + bias,
// written as packed bf16 pairs via sc1 (agent) stores. Called by all 512
// threads of a block; uses As/Bs (32KB) of smem.
// ---------------------------------------------------------------------------
__device__ __forceinline__ void gemm_tile(
    const unsigned short* __restrict__ XB, const unsigned short* __restrict__ WB,
    const float* __restrict__ bias, unsigned short* __restrict__ gi16,
    short* As, short* Bs, int m0, int n0, int t, int lane, int wave)
{
    const int lr = lane >> 3;             // 0..7
    const int lc = (lane & 7) * 8;        // bf16 col
    const int mb = (wave & 1) * 64;
    const int nb = (wave >> 1) * 32;

    f32x4 acc[4][2] = {};
    for (int k0 = 0; k0 < II; k0 += 64) {
        __syncthreads();
        #pragma unroll
        for (int p = 0; p < 2; ++p) {
            int sg = p * 8 + wave;        // 0..15, wave-uniform
            const unsigned short* ga = XB + (size_t)(m0 + sg * 8 + lr) * II + k0 + lc;
            const unsigned short* gb = WB + (size_t)(n0 + sg * 8 + lr) * II + k0 + lc;
            __builtin_amdgcn_global_load_lds(
                (const __attribute__((address_space(1))) void*)ga,
                (__attribute__((address_space(3))) void*)(As + sg * 512), 16, 0, 0);
            __builtin_amdgcn_global_load_lds(
                (const __attribute__((address_space(1))) void*)gb,
                (__attribute__((address_space(3))) void*)(Bs + sg * 512), 16, 0, 0);
        }
        __syncthreads();
        #pragma unroll
        for (int ks = 0; ks < 2; ++ks) {
            bf16x8 af[4], bf[2];
            #pragma unroll
            for (int i = 0; i < 4; ++i)
                af[i] = *reinterpret_cast<const bf16x8*>(
                    As + (mb + i * 16 + (lane & 15)) * 64 + ks * 32 + (lane >> 4) * 8);
            #pragma unroll
            for (int i = 0; i < 2; ++i)
                bf[i] = *reinterpret_cast<const bf16x8*>(
                    Bs + (nb + i * 16 + (lane & 15)) * 64 + ks * 32 + (lane >> 4) * 8);
            #pragma unroll
            for (int mi = 0; mi < 4; ++mi)
                #pragma unroll
                for (int ni = 0; ni < 2; ++ni)
                    acc[mi][ni] = __builtin_amdgcn_mfma_f32_16x16x32_bf16(
                        af[mi], bf[ni], acc[mi][ni], 0, 0, 0);
        }
    }
    // epilogue: bias add, bf16 pack across lane pairs, sc1 u32 stores
    #pragma unroll
    for (int ni = 0; ni < 2; ++ni) {
        int ncol = n0 + nb + ni * 16 + (lane & 15);
        float bv = bias[ncol];
        #pragma unroll
        for (int mi = 0; mi < 4; ++mi) {
            int mrow = m0 + mb + mi * 16 + ((lane >> 4) << 2);
            #pragma unroll
            for (int e = 0; e < 4; ++e) {
                float v = acc[mi][ni][e] + bv;
                unsigned short hb = f2b(v);
                unsigned pv = (unsigned)__shfl_xor((int)(unsigned)hb, 1);
                if (!(lane & 1)) {
                    unsigned word = (unsigned)hb | (pv << 16);
                    __hip_atomic_store(
                        (unsigned*)(gi16 + (size_t)(mrow + e) * G3 + ncol),
                        word, __ATOMIC_RELAXED, __HIP_MEMORY_SCOPE_AGENT);
                }
            }
        }
    }
}

// ---------------------------------------------------------------------------
// Kernel F: FUSED producer-consumer. Cooperative 256 blocks x 512 threads.
// Phase 0 (ALL blocks): 6 chunk-0 tiles each (256*6 = 1536 = whole chunk 0)
//   -> done[0] += 1 (target 256). Halves the priming delay.
// Then bid<128: scan role (proven r11 datapath, bf16 gi reads, chunk gates);
//      bid>=128: worker role — chunks 1..7, 12 jobs each -> done[c] += 1.
// ---------------------------------------------------------------------------
__global__ __launch_bounds__(512, 1)
void gru_fused(unsigned short* __restrict__ gi16,
               const unsigned short* __restrict__ XB,
               const unsigned short* __restrict__ WB, const float* __restrict__ bias,
               const float* __restrict__ Whh, const float* __restrict__ h0,
               unsigned short* __restrict__ h16, int* __restrict__ flags,
               float* __restrict__ out)
{
    __shared__ char smem[52224];
    const int t    = threadIdx.x;
    const int lane = t & 63;
    const int wave = t >> 6;          // 0..7
    const int bid  = blockIdx.x;

    short* As = (short*)smem;
    short* Bs = (short*)(smem + 16384);

    // ---- phase 0: all 256 blocks produce chunk 0 (tiles bid*6 .. bid*6+5) ----
    #pragma unroll 1
    for (int q = 0; q < 6; ++q) {
        int tile = bid * 6 + q;          // 0..1535
        int b = tile / 24, n = tile % 24;
        gemm_tile(XB, WB, bias, gi16, As, Bs, b * 1024, n * 128, t, lane, wave);
    }
    asm volatile("s_waitcnt vmcnt(0)" ::: "memory");
    __syncthreads();                     // all sc1 stores drained, smem free
    if (t == 0)
        __hip_atomic_fetch_add(&flags[2048], 1,
                               __ATOMIC_RELAXED, __HIP_MEMORY_SCOPE_AGENT);

    if (bid >= 128) {
        // =================== worker role: chunks 1..7 ===================
        const int wkr = bid - 128;
        #pragma unroll 1
        for (int jj = 0; jj < 84; ++jj) {
            int c   = 1 + jj / 12;
            int idx = (jj % 12) * 128 + wkr;     // 0..1535 within chunk
            int b = idx / 24, n = idx % 24;
            gemm_tile(XB, WB, bias, gi16, As, Bs,
                      b * 1024 + c * 128, n * 128, t, lane, wave);
            if ((jj % 12) == 11) {
                asm volatile("s_waitcnt vmcnt(0)" ::: "memory");
                __syncthreads();
                if (t == 0)
                    __hip_atomic_fetch_add(&flags[2048 + (c << 4)], 1,
                                           __ATOMIC_RELAXED, __HIP_MEMORY_SCOPE_AGENT);
            }
        }
        return;
    }

    // =================== scan role (proven r11 datapath) ===================
    auto part = reinterpret_cast<float(*)[6][4][68]>(smem);  // [8][6][4][68]

    const int group = bid & 3;
    const int jb    = bid >> 2;        // 0..31

    bf16x8 wf[4][6];
    #pragma unroll
    for (int kc = 0; kc < 4; ++kc) {
        #pragma unroll
        for (int nt = 0; nt < 6; ++nt) {
            int rowg = (nt >> 1) * HH + jb * 32 + (nt & 1) * 16 + (lane & 15);
            int k    = wave * 128 + kc * 32 + ((lane >> 4) << 3);
            const float4* src = reinterpret_cast<const float4*>(Whh + (size_t)rowg * HH + k);
            float4 f0 = src[0], f1 = src[1];
            bf16x8 w;
            w[0] = (short)f2b(f0.x); w[1] = (short)f2b(f0.y);
            w[2] = (short)f2b(f0.z); w[3] = (short)f2b(f0.w);
            w[4] = (short)f2b(f1.x); w[5] = (short)f2b(f1.y);
            w[6] = (short)f2b(f1.z); w[7] = (short)f2b(f1.w);
            wf[kc][nt] = w;
        }
    }

    const int b_l = t >> 5;
    const int j_l = t & 31;
    const int b_g = (group << 4) + b_l;
    const int j_g = (jb << 5) + j_l;
    float hreg = h0[b_g * HH + j_g];

    const int frag_base = (wave * 16 + (lane >> 4)) * 256 + ((lane & 15) << 4);
    const int prod_off  = ((j_g >> 3) << 8) + (b_l << 4) + ((j_g & 7) << 1);

    const int nt_r = j_l >> 4;
    const int lp   = ((b_l >> 2) << 4) | (j_l & 15);
    const int e_r  = b_l & 3;

    const int poll_fi = ((group << 5) | (wave << 2) | (lane & 3)) << 4;
    const int jeven = j_g & ~1;
    const int jsel  = (j_g & 1) << 4;   // 0 or 16 bit shift

    for (int s = 0; s < SS; ++s) {
        // chunk gate: gi chunk (s>>7) fully produced (chunk0 target 256)
        if ((s & 127) == 0) {
            const int target = (s == 0) ? 256 : 128;
            if (t == 0) {
                while (__hip_atomic_load(&flags[2048 + ((s >> 7) << 4)],
                                         __ATOMIC_RELAXED, __HIP_MEMORY_SCOPE_AGENT) < target)
                    __builtin_amdgcn_s_sleep(2);
            }
            __syncthreads();
        }

        const int p = s & 1;
        const char* rslab = (const char*)(h16 + (size_t)p * 65536 + group * 16384);
        unsigned short* wslab = h16 + (size_t)(p ^ 1) * 65536 + group * 16384;

        // prefetch gi (bf16 pairs, sc1: fresh across XCDs)
        size_t gib = ((size_t)b_g * SS + s) * G3;
        unsigned wr = __hip_atomic_load((const unsigned*)(gi16 + gib + jeven),
                                        __ATOMIC_RELAXED, __HIP_MEMORY_SCOPE_AGENT);
        unsigned wz = __hip_atomic_load((const unsigned*)(gi16 + gib + HH + jeven),
                                        __ATOMIC_RELAXED, __HIP_MEMORY_SCOPE_AGENT);
        unsigned wn = __hip_atomic_load((const unsigned*)(gi16 + gib + 2 * HH + jeven),
                                        __ATOMIC_RELAXED, __HIP_MEMORY_SCOPE_AGENT);
        float ir  = b2f((unsigned short)(wr >> jsel));
        float iz  = b2f((unsigned short)(wz >> jsel));
        float inn = b2f((unsigned short)(wn >> jsel));

        // fine poll: this wave's 4 producer blocks (minimal 1-load loop)
        if (s > 0) {
            while (true) {
                int v = __hip_atomic_load(&flags[poll_fi], __ATOMIC_RELAXED,
                                          __HIP_MEMORY_SCOPE_AGENT);
                if (__all(v >= s)) break;
            }
            asm volatile("" ::: "memory");
        }

        unsigned long long hv[8];
        #pragma unroll
        for (int kc = 0; kc < 4; ++kc) {
            const unsigned long long* q =
                (const unsigned long long*)(rslab + frag_base + kc * 1024);
            hv[2 * kc]     = __hip_atomic_load(q,     __ATOMIC_RELAXED,
                                               __HIP_MEMORY_SCOPE_AGENT);
            hv[2 * kc + 1] = __hip_atomic_load(q + 1, __ATOMIC_RELAXED,
                                               __HIP_MEMORY_SCOPE_AGENT);
        }

        f32x4 acc[6] = {};
        #pragma unroll
        for (int kc = 0; kc < 4; ++kc) {
            union { unsigned long long q[2]; bf16x8 v; } u;
            u.q[0] = hv[2 * kc]; u.q[1] = hv[2 * kc + 1];
            #pragma unroll
            for (int nt = 0; nt < 6; ++nt)
                acc[nt] = __builtin_amdgcn_mfma_f32_16x16x32_bf16(u.v, wf[kc][nt], acc[nt], 0, 0, 0);
        }

        #pragma unroll
        for (int nt = 0; nt < 6; ++nt)
            #pragma unroll
            for (int e = 0; e < 4; ++e)
                part[wave][nt][e][lane] = acc[nt][e];
        __syncthreads();   // bar1

        float hr = 0.f, hz = 0.f, hn = 0.f;
        #pragma unroll
        for (int w = 0; w < 8; ++w) {
            hr += part[w][0 + nt_r][e_r][lp];
            hz += part[w][2 + nt_r][e_r][lp];
            hn += part[w][4 + nt_r][e_r][lp];
        }

        float r  = __builtin_amdgcn_rcpf(1.f + __expf(-(ir + hr)));
        float z  = __builtin_amdgcn_rcpf(1.f + __expf(-(iz + hz)));
        float e2 = __expf(2.f * (inn + r * hn));
        float n  = 1.f - 2.f * __builtin_amdgcn_rcpf(e2 + 1.f);
        float hnew = (1.f - z) * n + z * hreg;
        hreg = hnew;

        unsigned short myb = f2b(hnew);
        unsigned pv = (unsigned)__shfl_xor((int)(unsigned)myb, 1);
        if (!(j_l & 1)) {
            unsigned val = ((unsigned)myb) | (pv << 16);
            __hip_atomic_store((unsigned*)((char*)wslab + prod_off), val,
                               __ATOMIC_RELAXED, __HIP_MEMORY_SCOPE_AGENT);
        }

        asm volatile("s_waitcnt vmcnt(0)" ::: "memory");
        __syncthreads();   // bar2
        if (t == 0)
            __hip_atomic_store(&flags[((group << 5) | jb) << 4], s + 1,
                               __ATOMIC_RELAXED, __HIP_MEMORY_SCOPE_AGENT);

        out[((size_t)b_g * SS + s) * HH + j_g] = hnew;
    }

    out[(size_t)BB * SS * HH + (size_t)b_g * HH + j_g] = hreg;
}

// ---------------------------------------------------------------------------
// Fallback (ws too small for xb/wb): old serial inline-convert GEMM + scan.
// ---------------------------------------------------------------------------
template<int GI_BF16>
__global__ __launch_bounds__(256)
void gi_gemm(const float* __restrict__ X, const float* __restrict__ W,
             const float* __restrict__ bias, void* __restrict__ gi_out)
{
    __shared__ short As[128][40];
    __shared__ short Bs[128][40];

    const int t    = threadIdx.x;
    const int lane = t & 63;
    const int wave = t >> 6;
    const int m0   = blockIdx.y * 128;
    const int n0   = blockIdx.x * 128;

    f32x4 acc[4][4] = {};

    for (int k0 = 0; k0 < II; k0 += 32) {
        __syncthreads();
        #pragma unroll
        for (int q = 0; q < 2; ++q) {
            int row = (t >> 2) + 64 * q;
            int col = (t & 3) * 8;
            const float4* ap = reinterpret_cast<const float4*>(X + (size_t)(m0 + row) * II + k0 + col);
            const float4* bp = reinterpret_cast<const float4*>(W + (size_t)(n0 + row) * II + k0 + col);
            float4 a0 = ap[0], a1 = ap[1];
            float4 b0 = bp[0], b1 = bp[1];
            bf16x8 av, bv;
            av[0] = (short)f2b(a0.x); av[1] = (short)f2b(a0.y);
            av[2] = (short)f2b(a0.z); av[3] = (short)f2b(a0.w);
            av[4] = (short)f2b(a1.x); av[5] = (short)f2b(a1.y);
            av[6] = (short)f2b(a1.z); av[7] = (short)f2b(a1.w);
            bv[0] = (short)f2b(b0.x); bv[1] = (short)f2b(b0.y);
            bv[2] = (short)f2b(b0.z); bv[3] = (short)f2b(b0.w);
            bv[4] = (short)f2b(b1.x); bv[5] = (short)f2b(b1.y);
            bv[6] = (short)f2b(b1.z); bv[7] = (short)f2b(b1.w);
            *reinterpret_cast<bf16x8*>(&As[row][col]) = av;
            *reinterpret_cast<bf16x8*>(&Bs[row][col]) = bv;
        }
        __syncthreads();

        const int mb = (wave & 1) * 64;
        const int nb = (wave >> 1) * 64;
        bf16x8 af[4], bf[4];
        #pragma unroll
        for (int i = 0; i < 4; ++i) {
            af[i] = *reinterpret_cast<const bf16x8*>(&As[mb + i * 16 + (lane & 15)][(lane >> 4) * 8]);
            bf[i] = *reinterpret_cast<const bf16x8*>(&Bs[nb + i * 16 + (lane & 15)][(lane >> 4) * 8]);
        }
        #pragma unroll
        for (int mi = 0; mi < 4; ++mi)
            #pragma unroll
            for (int ni = 0; ni < 4; ++ni)
                acc[mi][ni] = __builtin_amdgcn_mfma_f32_16x16x32_bf16(af[mi], bf[ni], acc[mi][ni], 0, 0, 0);
    }

    const int mb = (wave & 1) * 64;
    const int nb = (wave >> 1) * 64;
    #pragma unroll
    for (int ni = 0; ni < 4; ++ni) {
        int ncol = n0 + nb + ni * 16 + (lane & 15);
        float bv = bias[ncol];
        #pragma unroll
        for (int mi = 0; mi < 4; ++mi) {
            int mrow = m0 + mb + mi * 16 + ((lane >> 4) << 2);
            #pragma unroll
            for (int e = 0; e < 4; ++e) {
                float v = acc[mi][ni][e] + bv;
                size_t idx = (size_t)(mrow + e) * G3 + ncol;
                if (GI_BF16) ((unsigned short*)gi_out)[idx] = f2b(v);
                else         ((float*)gi_out)[idx] = v;
            }
        }
    }
}

template<int GI_BF16>
__global__ __launch_bounds__(512, 1)
void gru_scan(const void* __restrict__ gi_v, const float* __restrict__ Whh,
              const float* __restrict__ h0, unsigned short* __restrict__ h16,
              int* __restrict__ flags, float* __restrict__ out)
{
    const int t     = threadIdx.x;
    const int lane  = t & 63;
    const int wave  = t >> 6;
    const int bid   = blockIdx.x;
    const int group = bid & 3;
    const int jb    = bid >> 2;

    __shared__ float part[8][6][4][68];

    bf16x8 wf[4][6];
    #pragma unroll
    for (int kc = 0; kc < 4; ++kc) {
        #pragma unroll
        for (int nt = 0; nt < 6; ++nt) {
            int rowg = (nt >> 1) * HH + jb * 32 + (nt & 1) * 16 + (lane & 15);
            int k    = wave * 128 + kc * 32 + ((lane >> 4) << 3);
            const float4* src = reinterpret_cast<const float4*>(Whh + (size_t)rowg * HH + k);
            float4 f0 = src[0], f1 = src[1];
            bf16x8 w;
            w[0] = (short)f2b(f0.x); w[1] = (short)f2b(f0.y);
            w[2] = (short)f2b(f0.z); w[3] = (short)f2b(f0.w);
            w[4] = (short)f2b(f1.x); w[5] = (short)f2b(f1.y);
            w[6] = (short)f2b(f1.z); w[7] = (short)f2b(f1.w);
            wf[kc][nt] = w;
        }
    }

    const int b_l = t >> 5;
    const int j_l = t & 31;
    const int b_g = (group << 4) + b_l;
    const int j_g = (jb << 5) + j_l;
    float hreg = h0[b_g * HH + j_g];

    const int frag_base = (wave * 16 + (lane >> 4)) * 256 + ((lane & 15) << 4);
    const int prod_off  = ((j_g >> 3) << 8) + (b_l << 4) + ((j_g & 7) << 1);

    const int nt_r = j_l >> 4;
    const int lp   = ((b_l >> 2) << 4) | (j_l & 15);
    const int e_r  = b_l & 3;

    const int poll_fi = ((group << 5) | (wave << 2) | (lane & 3)) << 4;

    for (int s = 0; s < SS; ++s) {
        const int p = s & 1;
        const char* rslab = (const char*)(h16 + (size_t)p * 65536 + group * 16384);
        unsigned short* wslab = h16 + (size_t)(p ^ 1) * 65536 + group * 16384;

        size_t gib = ((size_t)b_g * SS + s) * G3;
        float ir, iz, inn;
        if (GI_BF16) {
            const unsigned short* g16 = (const unsigned short*)gi_v;
            ir  = b2f(g16[gib + j_g]);
            iz  = b2f(g16[gib + HH + j_g]);
            inn = b2f(g16[gib + 2 * HH + j_g]);
        } else {
            const float* g32 = (const float*)gi_v;
            ir  = g32[gib + j_g];
            iz  = g32[gib + HH + j_g];
            inn = g32[gib + 2 * HH + j_g];
        }

        if (s > 0) {
            while (true) {
                int v = __hip_atomic_load(&flags[poll_fi], __ATOMIC_RELAXED,
                                          __HIP_MEMORY_SCOPE_AGENT);
                if (__all(v >= s)) break;
            }
            asm volatile("" ::: "memory");
        }

        unsigned long long hv[8];
        #pragma unroll
        for (int kc = 0; kc < 4; ++kc) {
            const unsigned long long* q =
                (const unsigned long long*)(rslab + frag_base + kc * 1024);
            hv[2 * kc]     = __hip_atomic_load(q,     __ATOMIC_RELAXED,
                                               __HIP_MEMORY_SCOPE_AGENT);
            hv[2 * kc + 1] = __hip_atomic_load(q + 1, __ATOMIC_RELAXED,
                                               __HIP_MEMORY_SCOPE_AGENT);
        }

        f32x4 acc[6] = {};
        #pragma unroll
        for (int kc = 0; kc < 4; ++kc) {
            union { unsigned long long q[2]; bf16x8 v; } u;
            u.q[0] = hv[2 * kc]; u.q[1] = hv[2 * kc + 1];
            #pragma unroll
            for (int nt = 0; nt < 6; ++nt)
                acc[nt] = __builtin_amdgcn_mfma_f32_16x16x32_bf16(u.v, wf[kc][nt], acc[nt], 0, 0, 0);
        }

        #pragma unroll
        for (int nt = 0; nt < 6; ++nt)
            #pragma unroll
            for (int e = 0; e < 4; ++e)
                part[wave][nt][e][lane] = acc[nt][e];
        __syncthreads();

        float hr = 0.f, hz = 0.f, hn = 0.f;
        #pragma unroll
        for (int w = 0; w < 8; ++w) {
            hr += part[w][0 + nt_r][e_r][lp];
            hz += part[w][2 + nt_r][e_r][lp];
            hn += part[w][4 + nt_r][e_r][lp];
        }

        float r  = __builtin_amdgcn_rcpf(1.f + __expf(-(ir + hr)));
        float z  = __builtin_amdgcn_rcpf(1.f + __expf(-(iz + hz)));
        float e2 = __expf(2.f * (inn + r * hn));
        float n  = 1.f - 2.f * __builtin_amdgcn_rcpf(e2 + 1.f);
        float hnew = (1.f - z) * n + z * hreg;
        hreg = hnew;

        unsigned short myb = f2b(hnew);
        unsigned pv = (unsigned)__shfl_xor((int)(unsigned)myb, 1);
        if (!(j_l & 1)) {
            unsigned val = ((unsigned)myb) | (pv << 16);
            __hip_atomic_store((unsigned*)((char*)wslab + prod_off), val,
                               __ATOMIC_RELAXED, __HIP_MEMORY_SCOPE_AGENT);
        }

        asm volatile("s_waitcnt vmcnt(0)" ::: "memory");
        __syncthreads();
        if (t == 0)
            __hip_atomic_store(&flags[((group << 5) | jb) << 4], s + 1,
                               __ATOMIC_RELAXED, __HIP_MEMORY_SCOPE_AGENT);

        out[((size_t)b_g * SS + s) * HH + j_g] = hnew;
    }

    out[(size_t)BB * SS * HH + (size_t)b_g * HH + j_g] = hreg;
}

// ---------------------------------------------------------------------------
// Host launcher
// ---------------------------------------------------------------------------
extern "C" void kernel_launch(void* const* d_in, const int* in_sizes, int n_in,
                              void* d_out, int out_size, void* d_ws, size_t ws_size,
                              hipStream_t stream)
{
    const float* x   = (const float*)d_in[0];
    const float* h0  = (const float*)d_in[1];
    const float* Wih = (const float*)d_in[2];
    const float* Whh = (const float*)d_in[3];
    const float* bih = (const float*)d_in[4];
    float* out = (float*)d_out;

    char* ws = (char*)d_ws;
    unsigned short* h16 = (unsigned short*)ws;               // 2 x 128KiB parity bufs
    int* flags          = (int*)(ws + 262144);               // h-flags + chunk ctrs
    void* gi            = (void*)(ws + (1 << 20));           // 1 MiB offset

    const size_t gi32_bytes = (size_t)BB * SS * G3 * 4;      // 768 MiB
    const size_t gi16_bytes = gi32_bytes / 2;                // 384 MiB
    const size_t xb_off   = (size_t)(1 << 20) + gi32_bytes;
    const size_t wb_off   = xb_off + (size_t)BB * SS * II * 2;
    const size_t need_new = wb_off + (size_t)G3 * II * 2;

    const bool use_new = ws_size >= need_new;
    const bool use_f32 = !use_new && ws_size >= ((size_t)(1 << 20) + gi32_bytes);
    const bool use_b16 = !use_new && !use_f32 &&
                         ws_size >= ((size_t)(1 << 20) + gi16_bytes);
    if (!use_new && !use_f32 && !use_b16) return;

    gru_init<<<dim3(256), dim3(256), 0, stream>>>(h0, h16, flags);

    if (use_new) {
        unsigned short* xb = (unsigned short*)(ws + xb_off);
        unsigned short* wb = (unsigned short*)(ws + wb_off);
        conv_b16<<<dim3(68608), dim3(256), 0, stream>>>(x, Wih, xb, wb);
        unsigned short* gi16_p = (unsigned short*)gi;
        const unsigned short* xb_c = xb;
        const unsigned short* wb_c = wb;
        const float* bih_c = bih;
        const float* Whh_c = Whh;
        const float* h0_c = h0;
        unsigned short* h16_c = h16;
        int* flags_c = flags;
        float* out_c = out;
        void* args[] = { (void*)&gi16_p, (void*)&xb_c, (void*)&wb_c, (void*)&bih_c,
                         (void*)&Whh_c, (void*)&h0_c, (void*)&h16_c,
                         (void*)&flags_c, (void*)&out_c };
        hipLaunchCooperativeKernel((const void*)&gru_fused, dim3(256), dim3(512),
                                   args, 0, stream);
    } else {
        const void* gi_c = gi;
        const float* Whh_c = Whh;
        const float* h0_c = h0;
        unsigned short* h16_c = h16;
        int* flags_c = flags;
        float* out_c = out;
        void* args[] = { (void*)&gi_c, (void*)&Whh_c, (void*)&h0_c,
                         (void*)&h16_c, (void*)&flags_c, (void*)&out_c };
        if (use_f32) {
            gi_gemm<0><<<dim3(24, 512), dim3(256), 0, stream>>>(x, Wih, bih, gi);
            hipLaunchCooperativeKernel((const void*)&gru_scan<0>, dim3(128), dim3(512),
                                       args, 0, stream);
        } else {
            gi_gemm<1><<<dim3(24, 512), dim3(256), 0, stream>>>(x, Wih, bih, gi);
            hipLaunchCooperativeKernel((const void*)&gru_scan<1>, dim3(128), dim3(512),
                                       args, 0, stream);
        }
    }
}